// Round 5
// baseline (309.517 us; speedup 1.0000x reference)
//
#include <hip/hip_runtime.h>

// MultiHeadTEAttention: M=8, NQ=NKV=1024, DX=512, H=8, HD=64, KHID=16, DT=2
// f32 in/out; bf16 MFMA compute. Bias-MLP dot on matrix pipe.

typedef unsigned short u16;
typedef unsigned int   u32;
typedef short bf8 __attribute__((ext_vector_type(8)));   // 8 bf16 = 4 VGPR
typedef float f4  __attribute__((ext_vector_type(4)));

#define Mb 8
#define SCALE 0.125f

__device__ __forceinline__ u16 f2bf(float f) {
    union { float f; u32 u; } v; v.f = f;
    u32 r = v.u + 0x7fffu + ((v.u >> 16) & 1u);   // RNE
    return (u16)(r >> 16);
}
__device__ __forceinline__ u32 pk2(float a, float b) {
    return (u32)f2bf(a) | ((u32)f2bf(b) << 16);
}

// ===========================================================================
// Weight transpose+convert: Wt[n][k] bf16 = W[k][n] f32. 512x512, 4 matrices.
// ===========================================================================
__global__ __launch_bounds__(256) void wconv(
    const float* __restrict__ w0, const float* __restrict__ w1,
    const float* __restrict__ w2, const float* __restrict__ w3,
    u16* __restrict__ o0, u16* __restrict__ o1,
    u16* __restrict__ o2, u16* __restrict__ o3)
{
    const float* W[4] = {w0, w1, w2, w3};
    u16*         O[4] = {o0, o1, o2, o3};
    __shared__ float L[64][65];
    const int z = blockIdx.z, tid = threadIdx.x;
    const int k0 = blockIdx.x * 64, n0 = blockIdx.y * 64;
    const float* Wz = W[z];
    #pragma unroll
    for (int i = 0; i < 16; ++i) {
        int idx = tid + i * 256;
        int k = idx >> 6, n = idx & 63;
        L[n][k] = Wz[(size_t)(k0 + k) * 512 + n0 + n];
    }
    __syncthreads();
    u32* Oz = (u32*)O[z];
    #pragma unroll
    for (int i = 0; i < 8; ++i) {
        int idx = tid + i * 256;
        int n = idx >> 5, kp = idx & 31;
        Oz[((size_t)(n0 + n) * 512 + k0 + kp * 2) >> 1] = pk2(L[n][kp * 2], L[n][kp * 2 + 1]);
    }
}

// ===========================================================================
// GEMM: C = A[8192x512] @ Wt^T (+bias). A f32 or bf16; Wt bf16 [n][k].
// 128x128 tile, BK=32, LDS [seg(4)][row(128)][8 bf16].
// ===========================================================================
struct GArgs {
    const void* A[3];
    const u16*  W[3];
    void*       C[3];
    const float* bias;
    int modeT[3];
    int outf32;
    int abf16;
};

__global__ __launch_bounds__(256) void gemm_mfma(GArgs g) {
    __shared__ u16 Xs[4][128][8];
    __shared__ u16 Ws[4][128][8];

    const int z   = blockIdx.z;
    const int tid = threadIdx.x;
    const int w = tid >> 6, lane = tid & 63, quad = lane >> 4, l16 = lane & 15;
    const int wm = w >> 1, wn = w & 1;
    const int n0 = blockIdx.x * 128, t0 = blockIdx.y * 128;
    const int trans = g.modeT[z];

    f4 acc[4][4];
    #pragma unroll
    for (int i = 0; i < 4; ++i)
        #pragma unroll
        for (int j = 0; j < 4; ++j) acc[i][j] = (f4)0.f;

    const u16* Wp = g.W[z];

    for (int kc = 0; kc < 512; kc += 32) {
        __syncthreads();
        // ---- stage A tile (128 rows x 32 k) ----
        #pragma unroll
        for (int i = 0; i < 2; ++i) {
            const int cc = tid + i * 256;
            const int row = cc >> 2, seg = cc & 3;
            if (g.abf16) {
                const u16* ap = (const u16*)g.A[z] + (size_t)(t0 + row) * 512 + kc + seg * 8;
                *(uint4*)&Xs[seg][row][0] = *(const uint4*)ap;
            } else {
                const float* ap = (const float*)g.A[z] + (size_t)(t0 + row) * 512 + kc + seg * 8;
                float4 a0 = *(const float4*)ap;
                float4 a1 = *(const float4*)(ap + 4);
                uint4 v;
                v.x = pk2(a0.x, a0.y); v.y = pk2(a0.z, a0.w);
                v.z = pk2(a1.x, a1.y); v.w = pk2(a1.z, a1.w);
                *(uint4*)&Xs[seg][row][0] = v;
            }
        }
        // ---- stage W tile from Wt[n][k] ----
        #pragma unroll
        for (int i = 0; i < 2; ++i) {
            const int cc = tid + i * 256;
            const int row = cc >> 2, seg = cc & 3;
            const u16* bp = Wp + (size_t)(n0 + row) * 512 + kc + seg * 8;
            *(uint4*)&Ws[seg][row][0] = *(const uint4*)bp;
        }
        __syncthreads();

        const u16 (*Aop)[128][8] = trans ? Xs : Ws;
        const u16 (*Bop)[128][8] = trans ? Ws : Xs;
        const int arow = (trans ? wm : wn) * 64;
        const int brow = (trans ? wn : wm) * 64;
        bf8 af[4], bf[4];
        #pragma unroll
        for (int i = 0; i < 4; ++i) af[i] = *(const bf8*)&Aop[quad][arow + i * 16 + l16][0];
        #pragma unroll
        for (int j = 0; j < 4; ++j) bf[j] = *(const bf8*)&Bop[quad][brow + j * 16 + l16][0];
        #pragma unroll
        for (int i = 0; i < 4; ++i)
            #pragma unroll
            for (int j = 0; j < 4; ++j)
                acc[i][j] = __builtin_amdgcn_mfma_f32_16x16x32_bf16(af[i], bf[j], acc[i][j], 0, 0, 0);
    }

    if (g.outf32) {
        float* Co = (float*)g.C[z];
        #pragma unroll
        for (int i = 0; i < 4; ++i) {
            const int nb = n0 + wn * 64 + i * 16 + quad * 4;
            float4 bv = *(const float4*)&g.bias[nb];
            #pragma unroll
            for (int j = 0; j < 4; ++j) {
                const int tok = t0 + wm * 64 + j * 16 + l16;
                float4 st;
                st.x = acc[i][j][0] + bv.x; st.y = acc[i][j][1] + bv.y;
                st.z = acc[i][j][2] + bv.z; st.w = acc[i][j][3] + bv.w;
                *(float4*)&Co[(size_t)tok * 512 + nb] = st;
            }
        }
    } else if (!trans) {
        u16* C = (u16*)g.C[z];
        #pragma unroll
        for (int i = 0; i < 4; ++i) {
            const int nb = n0 + wn * 64 + i * 16 + quad * 4;
            #pragma unroll
            for (int j = 0; j < 4; ++j) {
                const int tok = t0 + wm * 64 + j * 16 + l16;
                uint2 pw;
                pw.x = pk2(acc[i][j][0], acc[i][j][1]);
                pw.y = pk2(acc[i][j][2], acc[i][j][3]);
                *(uint2*)&C[(size_t)tok * 512 + nb] = pw;
            }
        }
    } else {
        u16* Vt = (u16*)g.C[z];
        #pragma unroll
        for (int i = 0; i < 4; ++i) {
            const int tokb = t0 + wm * 64 + i * 16 + quad * 4;
            const int mb = tokb >> 10, tb = tokb & 1023;
            #pragma unroll
            for (int j = 0; j < 4; ++j) {
                const int n = n0 + wn * 64 + j * 16 + l16;
                uint2 pw;
                pw.x = pk2(acc[i][j][0], acc[i][j][1]);
                pw.y = pk2(acc[i][j][2], acc[i][j][3]);
                *(uint2*)&Vt[(size_t)mb * 524288 + (size_t)n * 1024 + tb] = pw;
            }
        }
    }
}

// ===========================================================================
// Fused attention v3: block = (m, 32-q tile), 512 threads = 8 waves = 8 heads.
// Bias MLP: relu in regs -> 16x16x32 MFMA (kw2 zero-padded) -> sB[k][h][q].
// K/V fragments loaded direct from global (L2-resident via XCD swizzle).
// ===========================================================================
__global__ __launch_bounds__(512) void attn_mfma(
    const u16* __restrict__ Q, const u16* __restrict__ K,
    const u16* __restrict__ Vt,
    const float* __restrict__ tqp, const float* __restrict__ tkp,
    const float* __restrict__ kw1, const float* __restrict__ kb1,
    const float* __restrict__ kw2,
    u16* __restrict__ O)
{
    __shared__ float sv[32][20];     // [k][c], padded (16B-aligned rows)
    __shared__ float sB[32][9][33];  // [k][h(pad9)][q], bias output
    __shared__ u16   sP[8][32][40];  // per-wave P [q][k], padded

    const int tid = threadIdx.x;
    const int w = tid >> 6, lane = tid & 63, quad = lane >> 4, l16 = lane & 15;
    const int m = blockIdx.x;              // XCD swizzle: gridDim.x=8 -> XCD ~ m
    const int q0 = blockIdx.y * 32;
    const int h = w;

    // ---- per-thread init ----
    // Q fragments: qf[qsub][kc]
    bf8 qf[2][2];
    #pragma unroll
    for (int qs = 0; qs < 2; ++qs)
        #pragma unroll
        for (int kc = 0; kc < 2; ++kc)
            qf[qs][kc] = *(const bf8*)(Q + ((size_t)m * 1024 + q0 + qs * 16 + l16) * 512
                                         + h * 64 + kc * 32 + quad * 8);
    // u[qsub][j]: c = (quad&1)*8 + j  (valid for quads 0,1)
    float u[2][8];
    {
        #pragma unroll
        for (int qs = 0; qs < 2; ++qs) {
            const size_t qi = ((size_t)m * 1024 + q0 + qs * 16 + l16) * 2;
            const float t0v = tqp[qi], t1v = tqp[qi + 1];
            #pragma unroll
            for (int j = 0; j < 8; ++j) {
                const int c = (quad & 1) * 8 + j;
                u[qs][j] = fmaf(t0v, kw1[c], fmaf(t1v, kw1[16 + c], kb1[c]));
            }
        }
    }
    // kw2 B-fragment (k = quad*8+j -> c, zero-padded c>=16; cols n = l16 = h)
    bf8 b2;
    {
        union { uint4 u4; bf8 v; } cv; cv.u4 = make_uint4(0, 0, 0, 0);
        if (l16 < 8 && quad < 2) {
            u32 r[4];
            #pragma unroll
            for (int p = 0; p < 4; ++p) {
                const int c = quad * 8 + p * 2;
                r[p] = pk2(kw2[c * 8 + l16], kw2[(c + 1) * 8 + l16]);
            }
            cv.u4 = make_uint4(r[0], r[1], r[2], r[3]);
        }
        b2 = cv.v;
    }
    // per-thread sv staging coords (512 threads: k = tid>>4, c = tid&15)
    const int svk = tid >> 4, svc = tid & 15;
    const float svw0 = kw1[svc], svw1 = kw1[16 + svc];

    float mrun[2] = {-1e30f, -1e30f}, lrun[2] = {0.f, 0.f};
    f4 o[2][4];
    #pragma unroll
    for (int qs = 0; qs < 2; ++qs)
        #pragma unroll
        for (int d = 0; d < 4; ++d) o[qs][d] = (f4)0.f;

    for (int kt = 0; kt < 32; ++kt) {
        const int k0 = kt * 32;

        // ---- direct-global K/V fragments (latency hidden by phases A+B) ----
        bf8 kf[2][2], vf[4];
        #pragma unroll
        for (int ms = 0; ms < 2; ++ms)
            #pragma unroll
            for (int kc = 0; kc < 2; ++kc)
                kf[ms][kc] = *(const bf8*)(K + ((size_t)m * 1024 + k0 + ms * 16 + l16) * 512
                                             + h * 64 + kc * 32 + quad * 8);
        #pragma unroll
        for (int ds = 0; ds < 4; ++ds)
            vf[ds] = *(const bf8*)(Vt + (size_t)m * 524288
                                      + (size_t)(h * 64 + ds * 16 + l16) * 1024 + k0 + quad * 8);

        // ---- phase A: stage sv[k][c] = tk[k] @ kw1[:,c] ----
        {
            const size_t ki = ((size_t)m * 1024 + k0 + svk) * 2;
            const float t0v = tkp[ki], t1v = tkp[ki + 1];
            sv[svk][svc] = fmaf(t0v, svw0, t1v * svw1);
        }
        __syncthreads();   // sv ready; all waves done with prev phase C (sB reads)

        // ---- phase B: bias MFMA. wave w handles k rows t = 4w..4w+3 ----
        #pragma unroll
        for (int tl = 0; tl < 4; ++tl) {
            const int t = w * 4 + tl;
            float4 v0, v1;
            if (quad < 2) {
                v0 = *(const float4*)&sv[t][quad * 8];
                v1 = *(const float4*)&sv[t][quad * 8 + 4];
            }
            #pragma unroll
            for (int qs = 0; qs < 2; ++qs) {
                union { uint4 u4; bf8 v; } cv; cv.u4 = make_uint4(0, 0, 0, 0);
                if (quad < 2) {
                    cv.u4.x = pk2(fmaxf(u[qs][0] - v0.x, 0.f), fmaxf(u[qs][1] - v0.y, 0.f));
                    cv.u4.y = pk2(fmaxf(u[qs][2] - v0.z, 0.f), fmaxf(u[qs][3] - v0.w, 0.f));
                    cv.u4.z = pk2(fmaxf(u[qs][4] - v1.x, 0.f), fmaxf(u[qs][5] - v1.y, 0.f));
                    cv.u4.w = pk2(fmaxf(u[qs][6] - v1.z, 0.f), fmaxf(u[qs][7] - v1.w, 0.f));
                }
                f4 d = __builtin_amdgcn_mfma_f32_16x16x32_bf16(cv.v, b2, (f4)0.f, 0, 0, 0);
                if (l16 < 8) {
                    #pragma unroll
                    for (int r = 0; r < 4; ++r)
                        sB[t][l16][qs * 16 + quad * 4 + r] = d[r];
                }
            }
        }
        __syncthreads();   // sB ready

        // ---- phase C: S^T, softmax, P·V (per wave = its head) ----
        #pragma unroll
        for (int qs = 0; qs < 2; ++qs) {
            f4 s[2];
            #pragma unroll
            for (int ms = 0; ms < 2; ++ms) {
                s[ms] = __builtin_amdgcn_mfma_f32_16x16x32_bf16(kf[ms][0], qf[qs][0], (f4)0.f, 0, 0, 0);
                s[ms] = __builtin_amdgcn_mfma_f32_16x16x32_bf16(kf[ms][1], qf[qs][1], s[ms], 0, 0, 0);
            }
            #pragma unroll
            for (int ms = 0; ms < 2; ++ms)
                #pragma unroll
                for (int r = 0; r < 4; ++r)
                    s[ms][r] = fmaf(s[ms][r], SCALE,
                                    sB[ms * 16 + quad * 4 + r][h][qs * 16 + l16]);
            // online softmax (keys spread over quads; cols q = l16)
            float mx = fmaxf(fmaxf(fmaxf(s[0][0], s[0][1]), fmaxf(s[0][2], s[0][3])),
                             fmaxf(fmaxf(s[1][0], s[1][1]), fmaxf(s[1][2], s[1][3])));
            mx = fmaxf(mx, __shfl_xor(mx, 16));
            mx = fmaxf(mx, __shfl_xor(mx, 32));
            const float mnew = fmaxf(mrun[qs], mx);
            const float alpha = __expf(mrun[qs] - mnew);
            float ps = 0.f;
            #pragma unroll
            for (int ms = 0; ms < 2; ++ms)
                #pragma unroll
                for (int r = 0; r < 4; ++r) {
                    float p = __expf(s[ms][r] - mnew);
                    s[ms][r] = p;
                    ps += p;
                }
            ps += __shfl_xor(ps, 16);
            ps += __shfl_xor(ps, 32);
            lrun[qs] = lrun[qs] * alpha + ps;
            mrun[qs] = mnew;
            #pragma unroll
            for (int ds = 0; ds < 4; ++ds) o[qs][ds] = o[qs][ds] * alpha;
            // P -> wave-private LDS (bf16)
            #pragma unroll
            for (int ms = 0; ms < 2; ++ms) {
                uint2 pw;
                pw.x = pk2(s[ms][0], s[ms][1]);
                pw.y = pk2(s[ms][2], s[ms][3]);
                *(uint2*)&sP[w][qs * 16 + l16][ms * 16 + quad * 4] = pw;
            }
            bf8 pf = *(const bf8*)&sP[w][qs * 16 + l16][quad * 8];
            #pragma unroll
            for (int ds = 0; ds < 4; ++ds)
                o[qs][ds] = __builtin_amdgcn_mfma_f32_16x16x32_bf16(vf[ds], pf, o[qs][ds], 0, 0, 0);
        }
    }

    // ---- epilogue: O[tok][h*64+d] = o/l (bf16) ----
    #pragma unroll
    for (int qs = 0; qs < 2; ++qs) {
        const float inv = 1.f / lrun[qs];
        u16* og = O + ((size_t)m * 1024 + q0 + qs * 16 + l16) * 512 + h * 64;
        #pragma unroll
        for (int ds = 0; ds < 4; ++ds) {
            uint2 pw;
            pw.x = pk2(o[qs][ds][0] * inv, o[qs][ds][1] * inv);
            pw.y = pk2(o[qs][ds][2] * inv, o[qs][ds][3] * inv);
            *(uint2*)(og + ds * 16 + quad * 4) = pw;
        }
    }
}

// ===========================================================================
extern "C" void kernel_launch(void* const* d_in, const int* in_sizes, int n_in,
                              void* d_out, int out_size, void* d_ws, size_t ws_size,
                              hipStream_t stream) {
    const float* xq    = (const float*)d_in[0];
    const float* xk    = (const float*)d_in[1];
    const float* xv    = (const float*)d_in[2];
    const float* tq    = (const float*)d_in[3];
    const float* tk    = (const float*)d_in[4];
    const float* w_q   = (const float*)d_in[5];
    const float* w_k   = (const float*)d_in[6];
    const float* w_v   = (const float*)d_in[7];
    const float* w_out = (const float*)d_in[8];
    const float* b_out = (const float*)d_in[9];
    const float* kw1   = (const float*)d_in[10];
    const float* kb1   = (const float*)d_in[11];
    const float* kw2   = (const float*)d_in[12];

    const size_t nTok = (size_t)Mb * 1024 * 512;   // 4,194,304
    u16* Q   = (u16*)d_ws;
    u16* Kp  = Q + nTok;
    u16* Vt  = Kp + nTok;
    u16* O   = Vt + nTok;
    u16* Wt0 = O + nTok;            // w_q^T
    u16* Wt1 = Wt0 + 512 * 512;
    u16* Wt2 = Wt1 + 512 * 512;
    u16* Wt3 = Wt2 + 512 * 512;     // w_out^T

    wconv<<<dim3(8, 8, 4), 256, 0, stream>>>(w_q, w_k, w_v, w_out, Wt0, Wt1, Wt2, Wt3);

    GArgs gq;
    gq.A[0] = xq;  gq.A[1] = xk;  gq.A[2] = xv;
    gq.W[0] = Wt0; gq.W[1] = Wt1; gq.W[2] = Wt2;
    gq.C[0] = Q;   gq.C[1] = Kp;  gq.C[2] = Vt;
    gq.bias = nullptr;
    gq.modeT[0] = 0; gq.modeT[1] = 0; gq.modeT[2] = 1;
    gq.outf32 = 0; gq.abf16 = 0;
    gemm_mfma<<<dim3(4, 64, 3), 256, 0, stream>>>(gq);

    attn_mfma<<<dim3(8, 32), 512, 0, stream>>>(Q, Kp, Vt, tq, tk, kw1, kb1, kw2, O);

    GArgs go;
    go.A[0] = O;   go.A[1] = O;   go.A[2] = O;
    go.W[0] = Wt3; go.W[1] = Wt3; go.W[2] = Wt3;
    go.C[0] = d_out; go.C[1] = d_out; go.C[2] = d_out;
    go.bias = b_out;
    go.modeT[0] = 0; go.modeT[1] = 0; go.modeT[2] = 0;
    go.outf32 = 1; go.abf16 = 1;
    gemm_mfma<<<dim3(4, 64, 1), 256, 0, stream>>>(go);
}